// Round 3
// baseline (562.707 us; speedup 1.0000x reference)
//
#include <hip/hip_runtime.h>
#include <hip/hip_bf16.h>
#include <cstdint>
#include <cstddef>

#define B_ 4
#define L_ 8192
#define D_ 512
#define H_ 1024
#define NC_ 32            // chunks along L for the 3-phase scan
#define LC_ (L_ / NC_)    // 256

typedef float  f32x4 __attribute__((ext_vector_type(4)));
typedef short  s16x8 __attribute__((ext_vector_type(8)));
typedef __bf16 b16x8 __attribute__((ext_vector_type(8)));

// ---- MFMA wrapper: tolerate either builtin signature (v8i16 or v8bf16) ----
template <typename T, typename U>
__device__ inline auto mfma_sel(T a, T b, f32x4 c, U, int)
    -> decltype(__builtin_amdgcn_mfma_f32_16x16x32_bf16(a, b, c, 0, 0, 0)) {
  return __builtin_amdgcn_mfma_f32_16x16x32_bf16(a, b, c, 0, 0, 0);
}
template <typename T, typename U>
__device__ inline f32x4 mfma_sel(T a, T b, f32x4 c, U, long) {
  return __builtin_amdgcn_mfma_f32_16x16x32_bf16(
      __builtin_bit_cast(U, a), __builtin_bit_cast(U, b), c, 0, 0, 0);
}
__device__ inline f32x4 mfma_bf16_16x16x32(s16x8 a, s16x8 b, f32x4 c) {
  return mfma_sel(a, b, c, b16x8{}, 0);
}

// ---- fp32 <-> bf16 ----
__device__ inline ushort f2bf(float f) {
  uint32_t u = __builtin_bit_cast(uint32_t, f);
  uint32_t r = (u + 0x7fffu + ((u >> 16) & 1u)) >> 16;
  return (ushort)r;
}
__device__ inline float bf2f(ushort u) {
  return __builtin_bit_cast(float, (uint32_t)u << 16);
}

__global__ void cast_kernel(const float* __restrict__ in, ushort* __restrict__ out, int n4) {
  int i = blockIdx.x * blockDim.x + threadIdx.x;
  if (i >= n4) return;
  float4 f = reinterpret_cast<const float4*>(in)[i];
  ushort4 o;
  o.x = f2bf(f.x); o.y = f2bf(f.y); o.z = f2bf(f.z); o.w = f2bf(f.w);
  reinterpret_cast<ushort4*>(out)[i] = o;
}

// both weights in one launch
__global__ void cast2_kernel(const float* __restrict__ in0, ushort* __restrict__ out0, int n4_0,
                             const float* __restrict__ in1, ushort* __restrict__ out1, int n4_1) {
  int i = blockIdx.x * blockDim.x + threadIdx.x;
  const float* in; ushort* out;
  if (i < n4_0) { in = in0; out = out0; }
  else { i -= n4_0; if (i >= n4_1) return; in = in1; out = out1; }
  float4 f = reinterpret_cast<const float4*>(in)[i];
  ushort4 o;
  o.x = f2bf(f.x); o.y = f2bf(f.y); o.z = f2bf(f.z); o.w = f2bf(f.w);
  reinterpret_cast<ushort4*>(out)[i] = o;
}

// ---- NT GEMM: C[m][n] = sum_k A[m][k]*Bm[n][k] + bias[n]; A:MxK, Bm:NxK (row-major bf16) ----
// 128x128 tile, BK=32, 4 waves (2x2), each wave 64x64 via 4x4 MFMA 16x16x32 tiles.
// MFMA operands SWAPPED (a=B-frag, b=A-frag) so D rows index n, cols index m:
// a lane's 4 acc regs = 4 consecutive n at fixed m -> packed wide stores.
// OUT_BF16: C is ushort* (bf16), else float*.
template <bool OUT_BF16>
__global__ __launch_bounds__(256)
void gemm_bt(const ushort* __restrict__ A, const ushort* __restrict__ Bm,
             const float* __restrict__ bias, void* __restrict__ Cv,
             int M, int N, int K) {
  __shared__ ushort As[128 * 32];
  __shared__ ushort Bs[128 * 32];
  const int tid  = threadIdx.x;
  const int wave = tid >> 6;
  const int lane = tid & 63;
  const int l15  = lane & 15;
  const int quad = lane >> 4;
  const long bm = (long)blockIdx.y * 128;
  const long bn = (long)blockIdx.x * 128;
  const int  wm = (wave >> 1) * 64;
  const int  wn = (wave & 1) * 64;

  f32x4 acc[4][4];
#pragma unroll
  for (int i = 0; i < 4; ++i)
#pragma unroll
    for (int j = 0; j < 4; ++j) acc[i][j] = (f32x4){0.f, 0.f, 0.f, 0.f};

  // staging: wave fills rows [wave*32, wave*32+32) of As/Bs; lane -> (row, 8-elem col)
  const int srow = wave * 32 + (lane >> 2);
  const int scol = (lane & 3) * 8;
  const ushort* gA0 = A  + (bm + srow) * (long)K + scol;
  const ushort* gB0 = Bm + (bn + srow) * (long)K + scol;
  ushort* lA0 = &As[(wave * 32) * 32];
  ushort* lA1 = &As[(wave * 32 + 16) * 32];
  ushort* lB0 = &Bs[(wave * 32) * 32];
  ushort* lB1 = &Bs[(wave * 32 + 16) * 32];

  for (int k0 = 0; k0 < K; k0 += 32) {
    __builtin_amdgcn_global_load_lds(
        (const __attribute__((address_space(1))) void*)(gA0 + k0),
        (__attribute__((address_space(3))) void*)lA0, 16, 0, 0);
    __builtin_amdgcn_global_load_lds(
        (const __attribute__((address_space(1))) void*)(gA0 + 16L * K + k0),
        (__attribute__((address_space(3))) void*)lA1, 16, 0, 0);
    __builtin_amdgcn_global_load_lds(
        (const __attribute__((address_space(1))) void*)(gB0 + k0),
        (__attribute__((address_space(3))) void*)lB0, 16, 0, 0);
    __builtin_amdgcn_global_load_lds(
        (const __attribute__((address_space(1))) void*)(gB0 + 16L * K + k0),
        (__attribute__((address_space(3))) void*)lB1, 16, 0, 0);
    __syncthreads();   // drains vmcnt -> LDS tile ready

    s16x8 af[4], bf[4];
#pragma unroll
    for (int mi = 0; mi < 4; ++mi)
      af[mi] = *reinterpret_cast<const s16x8*>(&As[(wm + mi * 16 + l15) * 32 + quad * 8]);
#pragma unroll
    for (int ni = 0; ni < 4; ++ni)
      bf[ni] = *reinterpret_cast<const s16x8*>(&Bs[(wn + ni * 16 + l15) * 32 + quad * 8]);
    // operand swap: a = B-frag (rows -> n), b = A-frag (cols -> m)
#pragma unroll
    for (int mi = 0; mi < 4; ++mi)
#pragma unroll
      for (int ni = 0; ni < 4; ++ni)
        acc[mi][ni] = mfma_bf16_16x16x32(bf[ni], af[mi], acc[mi][ni]);
    __syncthreads();   // protect LDS before next stage
  }

  // epilogue: D layout row(quad*4+reg) = n-offset, col(lane&15) = m-offset
#pragma unroll
  for (int mi = 0; mi < 4; ++mi) {
    const long m = bm + wm + mi * 16 + l15;
#pragma unroll
    for (int ni = 0; ni < 4; ++ni) {
      const long nbase = bn + wn + ni * 16 + quad * 4;
      const float4 bv = *reinterpret_cast<const float4*>(&bias[nbase]);
      if (OUT_BF16) {
        ushort4 o;
        o.x = f2bf(acc[mi][ni][0] + bv.x);
        o.y = f2bf(acc[mi][ni][1] + bv.y);
        o.z = f2bf(acc[mi][ni][2] + bv.z);
        o.w = f2bf(acc[mi][ni][3] + bv.w);
        *reinterpret_cast<ushort4*>((ushort*)Cv + m * (long)N + nbase) = o;
      } else {
        float4 o;
        o.x = acc[mi][ni][0] + bv.x;
        o.y = acc[mi][ni][1] + bv.y;
        o.z = acc[mi][ni][2] + bv.z;
        o.w = acc[mi][ni][3] + bv.w;
        *reinterpret_cast<float4*>((float*)Cv + m * (long)N + nbase) = o;
      }
    }
  }
}

// ---- scan helpers ----
__device__ inline float softplus_f(float x) {
  return fmaxf(x, 0.f) + __logf(1.f + __expf(-fabsf(x)));
}
__device__ inline float logaddexp_f(float a, float b) {
  float m = fmaxf(a, b);
  return m + __logf(1.f + __expf(-fabsf(a - b)));
}
// from (hidden, gate): lc = -softplus(g); v = log_z + log_tilde_h
__device__ inline void transform_f(float hd, float g, float& lc, float& v) {
  float sp = softplus_f(g);
  lc = -sp;
  float lz = g - sp;                       // -softplus(-g)
  float lth = (hd >= 0.f) ? __logf(hd + 0.5f) : (hd - softplus_f(hd));
  v = lz + lth;
}

// phase 1: per (b, chunk, h) compute chunk composition (Asum, Bv)
__global__ void scan_phase1(const ushort* __restrict__ hg,
                            float* __restrict__ Ac, float* __restrict__ Bc) {
  int gid = blockIdx.x * blockDim.x + threadIdx.x;  // B_*NC_*H_
  int h = gid & (H_ - 1);
  int c = (gid >> 10) & (NC_ - 1);
  int b = gid >> 15;
  const ushort* p = hg + ((size_t)(b * L_ + c * LC_) * (2 * H_)) + h;
  float Asum = 0.f, Bv = -INFINITY;
#pragma unroll 4
  for (int l = 0; l < LC_; ++l) {
    float hd = bf2f(p[0]), g = bf2f(p[H_]);
    float lc, v; transform_f(hd, g, lc, v);
    Asum += lc;
    Bv = logaddexp_f(Bv + lc, v);
    p += 2 * H_;
  }
  int o = (b * NC_ + c) * H_ + h;
  Ac[o] = Asum; Bc[o] = Bv;
}

// phase 2: per (b, h) exclusive scan over chunk summaries -> carry (incoming log_h per chunk)
__global__ void scan_phase2(const float* __restrict__ Ac, const float* __restrict__ Bc,
                            float* __restrict__ carry) {
  int gid = blockIdx.x * blockDim.x + threadIdx.x;  // B_*H_
  int h = gid & (H_ - 1);
  int b = gid >> 10;
  float P = -INFINITY;
  for (int c = 0; c < NC_; ++c) {
    int o = (b * NC_ + c) * H_ + h;
    carry[o] = P;
    P = logaddexp_f(P + Ac[o], Bc[o]);
  }
}

// phase 3: re-scan chunk with carry, emit h = exp(log_h) as bf16
__global__ void scan_phase3(const ushort* __restrict__ hg, const float* __restrict__ carry,
                            ushort* __restrict__ hb) {
  int gid = blockIdx.x * blockDim.x + threadIdx.x;  // B_*NC_*H_
  int h = gid & (H_ - 1);
  int c = (gid >> 10) & (NC_ - 1);
  int b = gid >> 15;
  float lh = carry[(b * NC_ + c) * H_ + h];
  const ushort* p = hg + ((size_t)(b * L_ + c * LC_) * (2 * H_)) + h;
  ushort* q = hb + (size_t)(b * L_ + c * LC_) * H_ + h;
#pragma unroll 4
  for (int l = 0; l < LC_; ++l) {
    float hd = bf2f(p[0]), g = bf2f(p[H_]);
    float lc, v; transform_f(hd, g, lc, v);
    lh = logaddexp_f(lh + lc, v);
    *q = f2bf(__expf(lh));
    p += 2 * H_;
    q += H_;
  }
}

extern "C" void kernel_launch(void* const* d_in, const int* in_sizes, int n_in,
                              void* d_out, int out_size, void* d_ws, size_t ws_size,
                              hipStream_t stream) {
  const float* x     = (const float*)d_in[0];
  const float* W_in  = (const float*)d_in[1];
  const float* b_in  = (const float*)d_in[2];
  const float* W_out = (const float*)d_in[3];
  const float* b_out = (const float*)d_in[4];
  float* out = (float*)d_out;

  char* ws = (char*)d_ws;
  size_t off = 0;
  auto alloc = [&](size_t bytes) {
    void* p = ws + off;
    off = (off + bytes + 255) & ~(size_t)255;
    return p;
  };
  // region shared by xb (alive: cast -> GEMM1) and hb (alive: phase3 -> GEMM2)
  ushort* xb    = (ushort*)alloc((size_t)B_ * L_ * H_ * 2);       // 67 MB (union)
  ushort* hb    = xb;
  ushort* Wib   = (ushort*)alloc((size_t)2 * H_ * D_ * 2);        // 2 MB
  ushort* Wob   = (ushort*)alloc((size_t)D_ * H_ * 2);            // 1 MB
  ushort* hgb   = (ushort*)alloc((size_t)B_ * L_ * 2 * H_ * 2);   // 134 MB (bf16)
  float*  Ac    = (float*)alloc((size_t)B_ * NC_ * H_ * 4);
  float*  Bc    = (float*)alloc((size_t)B_ * NC_ * H_ * 4);
  float*  carry = (float*)alloc((size_t)B_ * NC_ * H_ * 4);
  // total ~206 MB

  // casts to bf16
  cast_kernel<<<(B_ * L_ * D_ / 4 + 255) / 256, 256, 0, stream>>>(x, xb, B_ * L_ * D_ / 4);
  {
    int n0 = 2 * H_ * D_ / 4, n1 = D_ * H_ / 4;
    cast2_kernel<<<(n0 + n1 + 255) / 256, 256, 0, stream>>>(W_in, Wib, n0, W_out, Wob, n1);
  }

  // GEMM1: hg = x . W_in^T + b_in   (M=32768, N=2048, K=512), bf16 out
  gemm_bt<true><<<dim3((2 * H_) / 128, (B_ * L_) / 128), 256, 0, stream>>>(
      xb, Wib, b_in, hgb, B_ * L_, 2 * H_, D_);

  // chunked scan along L
  scan_phase1<<<(B_ * NC_ * H_) / 256, 256, 0, stream>>>(hgb, Ac, Bc);
  scan_phase2<<<(B_ * H_) / 256, 256, 0, stream>>>(Ac, Bc, carry);
  scan_phase3<<<(B_ * NC_ * H_) / 256, 256, 0, stream>>>(hgb, carry, hb);

  // GEMM2: out = h . W_out^T + b_out   (M=32768, N=512, K=1024), fp32 out
  gemm_bt<false><<<dim3(D_ / 128, (B_ * L_) / 128), 256, 0, stream>>>(
      hb, Wob, b_out, out, B_ * L_, D_, H_);
}

// Round 4
// 537.120 us; speedup vs baseline: 1.0476x; 1.0476x over previous
//
#include <hip/hip_runtime.h>
#include <hip/hip_bf16.h>
#include <cstdint>
#include <cstddef>

#define B_ 4
#define L_ 8192
#define D_ 512
#define H_ 1024
#define NC_ 32            // chunks along L for the 3-phase scan
#define LC_ (L_ / NC_)    // 256

typedef float  f32x4 __attribute__((ext_vector_type(4)));
typedef short  s16x8 __attribute__((ext_vector_type(8)));
typedef __bf16 b16x8 __attribute__((ext_vector_type(8)));

// ---- MFMA wrapper: tolerate either builtin signature (v8i16 or v8bf16) ----
template <typename T, typename U>
__device__ inline auto mfma_sel(T a, T b, f32x4 c, U, int)
    -> decltype(__builtin_amdgcn_mfma_f32_16x16x32_bf16(a, b, c, 0, 0, 0)) {
  return __builtin_amdgcn_mfma_f32_16x16x32_bf16(a, b, c, 0, 0, 0);
}
template <typename T, typename U>
__device__ inline f32x4 mfma_sel(T a, T b, f32x4 c, U, long) {
  return __builtin_amdgcn_mfma_f32_16x16x32_bf16(
      __builtin_bit_cast(U, a), __builtin_bit_cast(U, b), c, 0, 0, 0);
}
__device__ inline f32x4 mfma_bf16_16x16x32(s16x8 a, s16x8 b, f32x4 c) {
  return mfma_sel(a, b, c, b16x8{}, 0);
}

// ---- fp32 <-> bf16 ----
__device__ inline ushort f2bf(float f) {
  uint32_t u = __builtin_bit_cast(uint32_t, f);
  uint32_t r = (u + 0x7fffu + ((u >> 16) & 1u)) >> 16;
  return (ushort)r;
}
__device__ inline float bf2f(ushort u) {
  return __builtin_bit_cast(float, (uint32_t)u << 16);
}

__global__ void cast_kernel(const float* __restrict__ in, ushort* __restrict__ out, int n4) {
  int i = blockIdx.x * blockDim.x + threadIdx.x;
  if (i >= n4) return;
  float4 f = reinterpret_cast<const float4*>(in)[i];
  ushort4 o;
  o.x = f2bf(f.x); o.y = f2bf(f.y); o.z = f2bf(f.z); o.w = f2bf(f.w);
  reinterpret_cast<ushort4*>(out)[i] = o;
}

// both weights in one launch
__global__ void cast2_kernel(const float* __restrict__ in0, ushort* __restrict__ out0, int n4_0,
                             const float* __restrict__ in1, ushort* __restrict__ out1, int n4_1) {
  int i = blockIdx.x * blockDim.x + threadIdx.x;
  const float* in; ushort* out;
  if (i < n4_0) { in = in0; out = out0; }
  else { i -= n4_0; if (i >= n4_1) return; in = in1; out = out1; }
  float4 f = reinterpret_cast<const float4*>(in)[i];
  ushort4 o;
  o.x = f2bf(f.x); o.y = f2bf(f.y); o.z = f2bf(f.z); o.w = f2bf(f.w);
  reinterpret_cast<ushort4*>(out)[i] = o;
}

// ---- NT GEMM: C[m][n] = sum_k A[m][k]*Bm[n][k] + bias[n]; A:MxK, Bm:NxK (row-major bf16) ----
// 128x128 tile, BK=32, 4 waves (2x2), each wave 64x64 via 4x4 MFMA 16x16x32 tiles.
// LDS bank swizzle: logical 16B chunk q of row r lives at physical slot q ^ ((r>>1)&3).
// global_load_lds's LDS dest is lane-ordered, so we permute the GLOBAL source per lane.
// OUT_BF16: C is ushort* (bf16), else float*.
template <bool OUT_BF16>
__global__ __launch_bounds__(256)
void gemm_bt(const ushort* __restrict__ A, const ushort* __restrict__ Bm,
             const float* __restrict__ bias, void* __restrict__ Cv,
             int M, int N, int K) {
  __shared__ ushort As[128 * 32];
  __shared__ ushort Bs[128 * 32];
  const int tid  = threadIdx.x;
  const int wave = tid >> 6;
  const int lane = tid & 63;
  const int l15  = lane & 15;
  const int quad = lane >> 4;
  const long bm = (long)blockIdx.y * 128;
  const long bn = (long)blockIdx.x * 128;
  const int  wm = (wave >> 1) * 64;
  const int  wn = (wave & 1) * 64;

  f32x4 acc[4][4];
#pragma unroll
  for (int i = 0; i < 4; ++i)
#pragma unroll
    for (int j = 0; j < 4; ++j) acc[i][j] = (f32x4){0.f, 0.f, 0.f, 0.f};

  // staging: wave fills rows [wave*32, wave*32+32); lane -> (row rl, swizzled colblk)
  const int rl = lane >> 2;                       // 0..15
  const int cb = (lane & 3) ^ ((rl >> 1) & 3);    // swizzled global colblk for this lane
  const int srow = wave * 32 + rl;
  const ushort* gA0 = A  + (bm + srow) * (long)K + cb * 8;
  const ushort* gB0 = Bm + (bn + srow) * (long)K + cb * 8;
  ushort* lA0 = &As[(wave * 32) * 32];
  ushort* lA1 = &As[(wave * 32 + 16) * 32];
  ushort* lB0 = &Bs[(wave * 32) * 32];
  ushort* lB1 = &Bs[(wave * 32 + 16) * 32];

  // fragment-read swizzled slot (loop-invariant): quad ^ ((l15>>1)&3)
  const int sq = (quad ^ ((l15 >> 1) & 3)) * 8;

  for (int k0 = 0; k0 < K; k0 += 32) {
    __builtin_amdgcn_global_load_lds(
        (const __attribute__((address_space(1))) void*)(gA0 + k0),
        (__attribute__((address_space(3))) void*)lA0, 16, 0, 0);
    __builtin_amdgcn_global_load_lds(
        (const __attribute__((address_space(1))) void*)(gA0 + 16L * K + k0),
        (__attribute__((address_space(3))) void*)lA1, 16, 0, 0);
    __builtin_amdgcn_global_load_lds(
        (const __attribute__((address_space(1))) void*)(gB0 + k0),
        (__attribute__((address_space(3))) void*)lB0, 16, 0, 0);
    __builtin_amdgcn_global_load_lds(
        (const __attribute__((address_space(1))) void*)(gB0 + 16L * K + k0),
        (__attribute__((address_space(3))) void*)lB1, 16, 0, 0);
    __syncthreads();   // drains vmcnt -> LDS tile ready

    s16x8 af[4], bf[4];
#pragma unroll
    for (int mi = 0; mi < 4; ++mi)
      af[mi] = *reinterpret_cast<const s16x8*>(&As[(wm + mi * 16 + l15) * 32 + sq]);
#pragma unroll
    for (int ni = 0; ni < 4; ++ni)
      bf[ni] = *reinterpret_cast<const s16x8*>(&Bs[(wn + ni * 16 + l15) * 32 + sq]);
#pragma unroll
    for (int mi = 0; mi < 4; ++mi)
#pragma unroll
      for (int ni = 0; ni < 4; ++ni)
        acc[mi][ni] = mfma_bf16_16x16x32(af[mi], bf[ni], acc[mi][ni]);
    __syncthreads();   // protect LDS before next stage
  }

  // epilogue: C/D layout col = lane&15, row = quad*4 + reg
#pragma unroll
  for (int mi = 0; mi < 4; ++mi) {
    const long mrow = bm + wm + mi * 16 + quad * 4;
#pragma unroll
    for (int ni = 0; ni < 4; ++ni) {
      const long ncol = bn + wn + ni * 16 + l15;
      const float bv = bias[ncol];
      if (OUT_BF16) {
        ushort* cp = (ushort*)Cv + mrow * (long)N + ncol;
#pragma unroll
        for (int r = 0; r < 4; ++r) cp[(long)r * N] = f2bf(acc[mi][ni][r] + bv);
      } else {
        float* cp = (float*)Cv + mrow * (long)N + ncol;
#pragma unroll
        for (int r = 0; r < 4; ++r) cp[(long)r * N] = acc[mi][ni][r] + bv;
      }
    }
  }
}

// ---- scan helpers ----
__device__ inline float softplus_f(float x) {
  return fmaxf(x, 0.f) + __logf(1.f + __expf(-fabsf(x)));
}
__device__ inline float logaddexp_f(float a, float b) {
  float m = fmaxf(a, b);
  return m + __logf(1.f + __expf(-fabsf(a - b)));
}
// from (hidden, gate): lc = -softplus(g); v = log_z + log_tilde_h
__device__ inline void transform_f(float hd, float g, float& lc, float& v) {
  float sp = softplus_f(g);
  lc = -sp;
  float lz = g - sp;                       // -softplus(-g)
  float lth = (hd >= 0.f) ? __logf(hd + 0.5f) : (hd - softplus_f(hd));
  v = lz + lth;
}

// phase 1: per (b, chunk, h) compute chunk composition (Asum, Bv)
__global__ void scan_phase1(const ushort* __restrict__ hg,
                            float* __restrict__ Ac, float* __restrict__ Bc) {
  int gid = blockIdx.x * blockDim.x + threadIdx.x;  // B_*NC_*H_
  int h = gid & (H_ - 1);
  int c = (gid >> 10) & (NC_ - 1);
  int b = gid >> 15;
  const ushort* p = hg + ((size_t)(b * L_ + c * LC_) * (2 * H_)) + h;
  float Asum = 0.f, Bv = -INFINITY;
#pragma unroll 4
  for (int l = 0; l < LC_; ++l) {
    float hd = bf2f(p[0]), g = bf2f(p[H_]);
    float lc, v; transform_f(hd, g, lc, v);
    Asum += lc;
    Bv = logaddexp_f(Bv + lc, v);
    p += 2 * H_;
  }
  int o = (b * NC_ + c) * H_ + h;
  Ac[o] = Asum; Bc[o] = Bv;
}

// phase 2: per (b, h) exclusive scan over chunk summaries -> carry (incoming log_h per chunk)
__global__ void scan_phase2(const float* __restrict__ Ac, const float* __restrict__ Bc,
                            float* __restrict__ carry) {
  int gid = blockIdx.x * blockDim.x + threadIdx.x;  // B_*H_
  int h = gid & (H_ - 1);
  int b = gid >> 10;
  float P = -INFINITY;
  for (int c = 0; c < NC_; ++c) {
    int o = (b * NC_ + c) * H_ + h;
    carry[o] = P;
    P = logaddexp_f(P + Ac[o], Bc[o]);
  }
}

// phase 3: re-scan chunk with carry, emit h = exp(log_h) as bf16
__global__ void scan_phase3(const ushort* __restrict__ hg, const float* __restrict__ carry,
                            ushort* __restrict__ hb) {
  int gid = blockIdx.x * blockDim.x + threadIdx.x;  // B_*NC_*H_
  int h = gid & (H_ - 1);
  int c = (gid >> 10) & (NC_ - 1);
  int b = gid >> 15;
  float lh = carry[(b * NC_ + c) * H_ + h];
  const ushort* p = hg + ((size_t)(b * L_ + c * LC_) * (2 * H_)) + h;
  ushort* q = hb + (size_t)(b * L_ + c * LC_) * H_ + h;
#pragma unroll 4
  for (int l = 0; l < LC_; ++l) {
    float hd = bf2f(p[0]), g = bf2f(p[H_]);
    float lc, v; transform_f(hd, g, lc, v);
    lh = logaddexp_f(lh + lc, v);
    *q = f2bf(__expf(lh));
    p += 2 * H_;
    q += H_;
  }
}

extern "C" void kernel_launch(void* const* d_in, const int* in_sizes, int n_in,
                              void* d_out, int out_size, void* d_ws, size_t ws_size,
                              hipStream_t stream) {
  const float* x     = (const float*)d_in[0];
  const float* W_in  = (const float*)d_in[1];
  const float* b_in  = (const float*)d_in[2];
  const float* W_out = (const float*)d_in[3];
  const float* b_out = (const float*)d_in[4];
  float* out = (float*)d_out;

  char* ws = (char*)d_ws;
  size_t off = 0;
  auto alloc = [&](size_t bytes) {
    void* p = ws + off;
    off = (off + bytes + 255) & ~(size_t)255;
    return p;
  };
  // region shared by xb (alive: cast -> GEMM1) and hb (alive: phase3 -> GEMM2)
  ushort* xb    = (ushort*)alloc((size_t)B_ * L_ * H_ * 2);       // 67 MB (union)
  ushort* hb    = xb;
  ushort* Wib   = (ushort*)alloc((size_t)2 * H_ * D_ * 2);        // 2 MB
  ushort* Wob   = (ushort*)alloc((size_t)D_ * H_ * 2);            // 1 MB
  ushort* hgb   = (ushort*)alloc((size_t)B_ * L_ * 2 * H_ * 2);   // 134 MB (bf16)
  float*  Ac    = (float*)alloc((size_t)B_ * NC_ * H_ * 4);
  float*  Bc    = (float*)alloc((size_t)B_ * NC_ * H_ * 4);
  float*  carry = (float*)alloc((size_t)B_ * NC_ * H_ * 4);
  // total ~206 MB

  // casts to bf16
  cast_kernel<<<(B_ * L_ * D_ / 4 + 255) / 256, 256, 0, stream>>>(x, xb, B_ * L_ * D_ / 4);
  {
    int n0 = 2 * H_ * D_ / 4, n1 = D_ * H_ / 4;
    cast2_kernel<<<(n0 + n1 + 255) / 256, 256, 0, stream>>>(W_in, Wib, n0, W_out, Wob, n1);
  }

  // GEMM1: hg = x . W_in^T + b_in   (M=32768, N=2048, K=512), bf16 out
  gemm_bt<true><<<dim3((2 * H_) / 128, (B_ * L_) / 128), 256, 0, stream>>>(
      xb, Wib, b_in, hgb, B_ * L_, 2 * H_, D_);

  // chunked scan along L
  scan_phase1<<<(B_ * NC_ * H_) / 256, 256, 0, stream>>>(hgb, Ac, Bc);
  scan_phase2<<<(B_ * H_) / 256, 256, 0, stream>>>(Ac, Bc, carry);
  scan_phase3<<<(B_ * NC_ * H_) / 256, 256, 0, stream>>>(hgb, carry, hb);

  // GEMM2: out = h . W_out^T + b_out   (M=32768, N=512, K=1024), fp32 out
  gemm_bt<false><<<dim3(D_ / 128, (B_ * L_) / 128), 256, 0, stream>>>(
      hb, Wob, b_out, out, B_ * L_, D_, H_);
}

// Round 5
// 479.887 us; speedup vs baseline: 1.1726x; 1.1193x over previous
//
#include <hip/hip_runtime.h>
#include <hip/hip_bf16.h>
#include <cstdint>
#include <cstddef>

#define B_ 4
#define L_ 8192
#define D_ 512
#define H_ 1024
#define NC_ 256           // chunks along L for the 3-phase scan
#define LC_ (L_ / NC_)    // 32

typedef float  f32x4 __attribute__((ext_vector_type(4)));
typedef short  s16x8 __attribute__((ext_vector_type(8)));
typedef __bf16 b16x8 __attribute__((ext_vector_type(8)));

// ---- MFMA wrapper: tolerate either builtin signature (v8i16 or v8bf16) ----
template <typename T, typename U>
__device__ inline auto mfma_sel(T a, T b, f32x4 c, U, int)
    -> decltype(__builtin_amdgcn_mfma_f32_16x16x32_bf16(a, b, c, 0, 0, 0)) {
  return __builtin_amdgcn_mfma_f32_16x16x32_bf16(a, b, c, 0, 0, 0);
}
template <typename T, typename U>
__device__ inline f32x4 mfma_sel(T a, T b, f32x4 c, U, long) {
  return __builtin_amdgcn_mfma_f32_16x16x32_bf16(
      __builtin_bit_cast(U, a), __builtin_bit_cast(U, b), c, 0, 0, 0);
}
__device__ inline f32x4 mfma_bf16_16x16x32(s16x8 a, s16x8 b, f32x4 c) {
  return mfma_sel(a, b, c, b16x8{}, 0);
}

// ---- fp32 <-> bf16 ----
__device__ inline ushort f2bf(float f) {
  uint32_t u = __builtin_bit_cast(uint32_t, f);
  uint32_t r = (u + 0x7fffu + ((u >> 16) & 1u)) >> 16;
  return (ushort)r;
}
__device__ inline float bf2f(ushort u) {
  return __builtin_bit_cast(float, (uint32_t)u << 16);
}

__global__ void cast_kernel(const float* __restrict__ in, ushort* __restrict__ out, int n4) {
  int i = blockIdx.x * blockDim.x + threadIdx.x;
  if (i >= n4) return;
  float4 f = reinterpret_cast<const float4*>(in)[i];
  ushort4 o;
  o.x = f2bf(f.x); o.y = f2bf(f.y); o.z = f2bf(f.z); o.w = f2bf(f.w);
  reinterpret_cast<ushort4*>(out)[i] = o;
}

// both weights in one launch
__global__ void cast2_kernel(const float* __restrict__ in0, ushort* __restrict__ out0, int n4_0,
                             const float* __restrict__ in1, ushort* __restrict__ out1, int n4_1) {
  int i = blockIdx.x * blockDim.x + threadIdx.x;
  const float* in; ushort* out;
  if (i < n4_0) { in = in0; out = out0; }
  else { i -= n4_0; if (i >= n4_1) return; in = in1; out = out1; }
  float4 f = reinterpret_cast<const float4*>(in)[i];
  ushort4 o;
  o.x = f2bf(f.x); o.y = f2bf(f.y); o.z = f2bf(f.z); o.w = f2bf(f.w);
  reinterpret_cast<ushort4*>(out)[i] = o;
}

// ---- NT GEMM: C[m][n] = sum_k A[m][k]*Bm[n][k] + bias[n]; A:MxK, Bm:NxK (row-major bf16) ----
// 128x128 tile, BK=32, 4 waves (2x2), each wave 64x64 via 4x4 MFMA 16x16x32 tiles.
// LDS bank swizzle: logical 16B chunk q of row r lives at physical slot q ^ ((r>>1)&3)
// (conflict count verified 8.39M -> 0). global source permuted per-lane to compensate.
// OUT_BF16: C is ushort* (bf16), else float*.
template <bool OUT_BF16>
__global__ __launch_bounds__(256)
void gemm_bt(const ushort* __restrict__ A, const ushort* __restrict__ Bm,
             const float* __restrict__ bias, void* __restrict__ Cv,
             int M, int N, int K) {
  __shared__ ushort As[128 * 32];
  __shared__ ushort Bs[128 * 32];
  const int tid  = threadIdx.x;
  const int wave = tid >> 6;
  const int lane = tid & 63;
  const int l15  = lane & 15;
  const int quad = lane >> 4;
  const long bm = (long)blockIdx.y * 128;
  const long bn = (long)blockIdx.x * 128;
  const int  wm = (wave >> 1) * 64;
  const int  wn = (wave & 1) * 64;

  f32x4 acc[4][4];
#pragma unroll
  for (int i = 0; i < 4; ++i)
#pragma unroll
    for (int j = 0; j < 4; ++j) acc[i][j] = (f32x4){0.f, 0.f, 0.f, 0.f};

  // staging: wave fills rows [wave*32, wave*32+32); lane -> (row rl, swizzled colblk)
  const int rl = lane >> 2;                       // 0..15
  const int cb = (lane & 3) ^ ((rl >> 1) & 3);    // swizzled global colblk for this lane
  const int srow = wave * 32 + rl;
  const ushort* gA0 = A  + (bm + srow) * (long)K + cb * 8;
  const ushort* gB0 = Bm + (bn + srow) * (long)K + cb * 8;
  ushort* lA0 = &As[(wave * 32) * 32];
  ushort* lA1 = &As[(wave * 32 + 16) * 32];
  ushort* lB0 = &Bs[(wave * 32) * 32];
  ushort* lB1 = &Bs[(wave * 32 + 16) * 32];

  // fragment-read swizzled slot (loop-invariant): quad ^ ((l15>>1)&3)
  const int sq = (quad ^ ((l15 >> 1) & 3)) * 8;

  for (int k0 = 0; k0 < K; k0 += 32) {
    __builtin_amdgcn_global_load_lds(
        (const __attribute__((address_space(1))) void*)(gA0 + k0),
        (__attribute__((address_space(3))) void*)lA0, 16, 0, 0);
    __builtin_amdgcn_global_load_lds(
        (const __attribute__((address_space(1))) void*)(gA0 + 16L * K + k0),
        (__attribute__((address_space(3))) void*)lA1, 16, 0, 0);
    __builtin_amdgcn_global_load_lds(
        (const __attribute__((address_space(1))) void*)(gB0 + k0),
        (__attribute__((address_space(3))) void*)lB0, 16, 0, 0);
    __builtin_amdgcn_global_load_lds(
        (const __attribute__((address_space(1))) void*)(gB0 + 16L * K + k0),
        (__attribute__((address_space(3))) void*)lB1, 16, 0, 0);
    __syncthreads();   // drains vmcnt -> LDS tile ready

    s16x8 af[4], bf[4];
#pragma unroll
    for (int mi = 0; mi < 4; ++mi)
      af[mi] = *reinterpret_cast<const s16x8*>(&As[(wm + mi * 16 + l15) * 32 + sq]);
#pragma unroll
    for (int ni = 0; ni < 4; ++ni)
      bf[ni] = *reinterpret_cast<const s16x8*>(&Bs[(wn + ni * 16 + l15) * 32 + sq]);
#pragma unroll
    for (int mi = 0; mi < 4; ++mi)
#pragma unroll
      for (int ni = 0; ni < 4; ++ni)
        acc[mi][ni] = mfma_bf16_16x16x32(af[mi], bf[ni], acc[mi][ni]);
    __syncthreads();   // protect LDS before next stage
  }

  // epilogue: C/D layout col = lane&15, row = quad*4 + reg
#pragma unroll
  for (int mi = 0; mi < 4; ++mi) {
    const long mrow = bm + wm + mi * 16 + quad * 4;
#pragma unroll
    for (int ni = 0; ni < 4; ++ni) {
      const long ncol = bn + wn + ni * 16 + l15;
      const float bv = bias[ncol];
      if (OUT_BF16) {
        ushort* cp = (ushort*)Cv + mrow * (long)N + ncol;
#pragma unroll
        for (int r = 0; r < 4; ++r) cp[(long)r * N] = f2bf(acc[mi][ni][r] + bv);
      } else {
        float* cp = (float*)Cv + mrow * (long)N + ncol;
#pragma unroll
        for (int r = 0; r < 4; ++r) cp[(long)r * N] = acc[mi][ni][r] + bv;
      }
    }
  }
}

// ---- scan helpers ----
__device__ inline float softplus_f(float x) {
  return fmaxf(x, 0.f) + __logf(1.f + __expf(-fabsf(x)));
}
__device__ inline float logaddexp_f(float a, float b) {
  float m = fmaxf(a, b);
  return m + __logf(1.f + __expf(-fabsf(a - b)));
}
// from (hidden, gate): lc = -softplus(g); v = log_z + log_tilde_h
__device__ inline void transform_f(float hd, float g, float& lc, float& v) {
  float sp = softplus_f(g);
  lc = -sp;
  float lz = g - sp;                       // -softplus(-g)
  float lth = (hd >= 0.f) ? __logf(hd + 0.5f) : (hd - softplus_f(hd));
  v = lz + lth;
}

// phase 1: per (b, chunk, h-quad) compute chunk composition (Asum, Bv) for 4 channels
__global__ void scan_phase1(const ushort* __restrict__ hg,
                            float* __restrict__ Ac, float* __restrict__ Bc) {
  int gid = blockIdx.x * blockDim.x + threadIdx.x;  // B_*NC_*H_/4
  int hq = gid & (H_ / 4 - 1);       // h/4, 0..255
  int c  = (gid >> 8) & (NC_ - 1);
  int b  = gid >> 16;
  const ushort* p = hg + ((size_t)(b * L_ + c * LC_) * (2 * H_)) + hq * 4;
  float As[4] = {0.f, 0.f, 0.f, 0.f};
  float Bv[4] = {-INFINITY, -INFINITY, -INFINITY, -INFINITY};
#pragma unroll 4
  for (int l = 0; l < LC_; ++l) {
    ushort4 hd4 = *reinterpret_cast<const ushort4*>(p);
    ushort4 g4  = *reinterpret_cast<const ushort4*>(p + H_);
    float hdv[4] = {bf2f(hd4.x), bf2f(hd4.y), bf2f(hd4.z), bf2f(hd4.w)};
    float gv[4]  = {bf2f(g4.x),  bf2f(g4.y),  bf2f(g4.z),  bf2f(g4.w)};
#pragma unroll
    for (int j = 0; j < 4; ++j) {
      float lc, v; transform_f(hdv[j], gv[j], lc, v);
      As[j] += lc;
      Bv[j] = logaddexp_f(Bv[j] + lc, v);
    }
    p += 2 * H_;
  }
  size_t o = (size_t)(b * NC_ + c) * H_ + hq * 4;
  *reinterpret_cast<float4*>(&Ac[o]) = make_float4(As[0], As[1], As[2], As[3]);
  *reinterpret_cast<float4*>(&Bc[o]) = make_float4(Bv[0], Bv[1], Bv[2], Bv[3]);
}

// phase 2: per (b, h) exclusive scan over chunk summaries -> carry (incoming log_h per chunk)
__global__ void scan_phase2(const float* __restrict__ Ac, const float* __restrict__ Bc,
                            float* __restrict__ carry) {
  int gid = blockIdx.x * blockDim.x + threadIdx.x;  // B_*H_
  int h = gid & (H_ - 1);
  int b = gid >> 10;
  float P = -INFINITY;
  for (int c = 0; c < NC_; ++c) {
    size_t o = (size_t)(b * NC_ + c) * H_ + h;
    carry[o] = P;
    P = logaddexp_f(P + Ac[o], Bc[o]);
  }
}

// phase 3: re-scan chunk with carry, emit h = exp(log_h) as bf16 (4 channels/thread)
__global__ void scan_phase3(const ushort* __restrict__ hg, const float* __restrict__ carry,
                            ushort* __restrict__ hb) {
  int gid = blockIdx.x * blockDim.x + threadIdx.x;  // B_*NC_*H_/4
  int hq = gid & (H_ / 4 - 1);
  int c  = (gid >> 8) & (NC_ - 1);
  int b  = gid >> 16;
  float4 cr = *reinterpret_cast<const float4*>(&carry[(size_t)(b * NC_ + c) * H_ + hq * 4]);
  float lh[4] = {cr.x, cr.y, cr.z, cr.w};
  const ushort* p = hg + ((size_t)(b * L_ + c * LC_) * (2 * H_)) + hq * 4;
  ushort* q = hb + (size_t)(b * L_ + c * LC_) * H_ + hq * 4;
#pragma unroll 4
  for (int l = 0; l < LC_; ++l) {
    ushort4 hd4 = *reinterpret_cast<const ushort4*>(p);
    ushort4 g4  = *reinterpret_cast<const ushort4*>(p + H_);
    float hdv[4] = {bf2f(hd4.x), bf2f(hd4.y), bf2f(hd4.z), bf2f(hd4.w)};
    float gv[4]  = {bf2f(g4.x),  bf2f(g4.y),  bf2f(g4.z),  bf2f(g4.w)};
    ushort4 o;
    ushort* op = &o.x;
#pragma unroll
    for (int j = 0; j < 4; ++j) {
      float lc, v; transform_f(hdv[j], gv[j], lc, v);
      lh[j] = logaddexp_f(lh[j] + lc, v);
      op[j] = f2bf(__expf(lh[j]));
    }
    *reinterpret_cast<ushort4*>(q) = o;
    p += 2 * H_;
    q += H_;
  }
}

extern "C" void kernel_launch(void* const* d_in, const int* in_sizes, int n_in,
                              void* d_out, int out_size, void* d_ws, size_t ws_size,
                              hipStream_t stream) {
  const float* x     = (const float*)d_in[0];
  const float* W_in  = (const float*)d_in[1];
  const float* b_in  = (const float*)d_in[2];
  const float* W_out = (const float*)d_in[3];
  const float* b_out = (const float*)d_in[4];
  float* out = (float*)d_out;

  char* ws = (char*)d_ws;
  size_t off = 0;
  auto alloc = [&](size_t bytes) {
    void* p = ws + off;
    off = (off + bytes + 255) & ~(size_t)255;
    return p;
  };
  // region shared by xb (alive: cast -> GEMM1) and hb (alive: phase3 -> GEMM2)
  ushort* xb    = (ushort*)alloc((size_t)B_ * L_ * H_ * 2);       // 67 MB (union)
  ushort* hb    = xb;
  ushort* Wib   = (ushort*)alloc((size_t)2 * H_ * D_ * 2);        // 2 MB
  ushort* Wob   = (ushort*)alloc((size_t)D_ * H_ * 2);            // 1 MB
  ushort* hgb   = (ushort*)alloc((size_t)B_ * L_ * 2 * H_ * 2);   // 134 MB (bf16)
  float*  Ac    = (float*)alloc((size_t)B_ * NC_ * H_ * 4);       // 4 MB
  float*  Bc    = (float*)alloc((size_t)B_ * NC_ * H_ * 4);       // 4 MB
  float*  carry = (float*)alloc((size_t)B_ * NC_ * H_ * 4);       // 4 MB
  // total ~216 MB

  // casts to bf16
  cast_kernel<<<(B_ * L_ * D_ / 4 + 255) / 256, 256, 0, stream>>>(x, xb, B_ * L_ * D_ / 4);
  {
    int n0 = 2 * H_ * D_ / 4, n1 = D_ * H_ / 4;
    cast2_kernel<<<(n0 + n1 + 255) / 256, 256, 0, stream>>>(W_in, Wib, n0, W_out, Wob, n1);
  }

  // GEMM1: hg = x . W_in^T + b_in   (M=32768, N=2048, K=512), bf16 out
  gemm_bt<true><<<dim3((2 * H_) / 128, (B_ * L_) / 128), 256, 0, stream>>>(
      xb, Wib, b_in, hgb, B_ * L_, 2 * H_, D_);

  // chunked scan along L (4 channels per thread)
  scan_phase1<<<(B_ * NC_ * H_ / 4) / 256, 256, 0, stream>>>(hgb, Ac, Bc);
  scan_phase2<<<(B_ * H_) / 256, 256, 0, stream>>>(Ac, Bc, carry);
  scan_phase3<<<(B_ * NC_ * H_ / 4) / 256, 256, 0, stream>>>(hgb, carry, hb);

  // GEMM2: out = h . W_out^T + b_out   (M=32768, N=512, K=1024), fp32 out
  gemm_bt<false><<<dim3(D_ / 128, (B_ * L_) / 128), 256, 0, stream>>>(
      hb, Wob, b_out, out, B_ * L_, D_, H_);
}

// Round 6
// 454.986 us; speedup vs baseline: 1.2368x; 1.0547x over previous
//
#include <hip/hip_runtime.h>
#include <hip/hip_bf16.h>
#include <cstdint>
#include <cstddef>

#define B_ 4
#define L_ 8192
#define D_ 512
#define H_ 1024
#define NC_ 256           // chunks along L for the 3-phase scan
#define LC_ (L_ / NC_)    // 32

typedef float  f32x4 __attribute__((ext_vector_type(4)));
typedef short  s16x8 __attribute__((ext_vector_type(8)));
typedef __bf16 b16x8 __attribute__((ext_vector_type(8)));

// ---- MFMA wrapper: tolerate either builtin signature (v8i16 or v8bf16) ----
template <typename T, typename U>
__device__ inline auto mfma_sel(T a, T b, f32x4 c, U, int)
    -> decltype(__builtin_amdgcn_mfma_f32_16x16x32_bf16(a, b, c, 0, 0, 0)) {
  return __builtin_amdgcn_mfma_f32_16x16x32_bf16(a, b, c, 0, 0, 0);
}
template <typename T, typename U>
__device__ inline f32x4 mfma_sel(T a, T b, f32x4 c, U, long) {
  return __builtin_amdgcn_mfma_f32_16x16x32_bf16(
      __builtin_bit_cast(U, a), __builtin_bit_cast(U, b), c, 0, 0, 0);
}
__device__ inline f32x4 mfma_bf16_16x16x32(s16x8 a, s16x8 b, f32x4 c) {
  return mfma_sel(a, b, c, b16x8{}, 0);
}

// ---- fp32 <-> bf16 ----
__device__ inline ushort f2bf(float f) {
  uint32_t u = __builtin_bit_cast(uint32_t, f);
  uint32_t r = (u + 0x7fffu + ((u >> 16) & 1u)) >> 16;
  return (ushort)r;
}
__device__ inline float bf2f(ushort u) {
  return __builtin_bit_cast(float, (uint32_t)u << 16);
}

__global__ void cast_kernel(const float* __restrict__ in, ushort* __restrict__ out, int n4) {
  int i = blockIdx.x * blockDim.x + threadIdx.x;
  if (i >= n4) return;
  float4 f = reinterpret_cast<const float4*>(in)[i];
  ushort4 o;
  o.x = f2bf(f.x); o.y = f2bf(f.y); o.z = f2bf(f.z); o.w = f2bf(f.w);
  reinterpret_cast<ushort4*>(out)[i] = o;
}

// both weights in one launch
__global__ void cast2_kernel(const float* __restrict__ in0, ushort* __restrict__ out0, int n4_0,
                             const float* __restrict__ in1, ushort* __restrict__ out1, int n4_1) {
  int i = blockIdx.x * blockDim.x + threadIdx.x;
  const float* in; ushort* out;
  if (i < n4_0) { in = in0; out = out0; }
  else { i -= n4_0; if (i >= n4_1) return; in = in1; out = out1; }
  float4 f = reinterpret_cast<const float4*>(in)[i];
  ushort4 o;
  o.x = f2bf(f.x); o.y = f2bf(f.y); o.z = f2bf(f.z); o.w = f2bf(f.w);
  reinterpret_cast<ushort4*>(out)[i] = o;
}

// ---- NT GEMM: C[m][n] = sum_k A[m][k]*Bm[n][k] + bias[n]; A:MxK, Bm:NxK (row-major bf16) ----
// 128x128 tile, BK=64 (32 KB LDS; occupancy still 5 blk/CU, VGPR-capped), 4 waves (2x2),
// each wave 64x64 via 4x4 MFMA 16x16x32 tiles, 2 k-halves per iteration.
// LDS bank swizzle (128B rows, 8x16B slots): physical slot p of row r holds logical
// chunk p ^ (r&7). Staging lane (rl=lane>>3, slot=lane&7) fetches global chunk slot^rl;
// fragment read uses slot (kh*4+quad) ^ (l15&7) -> 2 lanes/slot = 2-way = free.
// OUT_BF16: C is ushort* (bf16), else float*.
template <bool OUT_BF16>
__global__ __launch_bounds__(256)
void gemm_bt(const ushort* __restrict__ A, const ushort* __restrict__ Bm,
             const float* __restrict__ bias, void* __restrict__ Cv,
             int M, int N, int K) {
  __shared__ ushort As[128 * 64];
  __shared__ ushort Bs[128 * 64];
  const int tid  = threadIdx.x;
  const int wave = tid >> 6;
  const int lane = tid & 63;
  const int l15  = lane & 15;
  const int quad = lane >> 4;
  const long bm = (long)blockIdx.y * 128;
  const long bn = (long)blockIdx.x * 128;
  const int  wm = (wave >> 1) * 64;
  const int  wn = (wave & 1) * 64;

  f32x4 acc[4][4];
#pragma unroll
  for (int i = 0; i < 4; ++i)
#pragma unroll
    for (int j = 0; j < 4; ++j) acc[i][j] = (f32x4){0.f, 0.f, 0.f, 0.f};

  // staging: wave fills rows [wave*32, wave*32+32); each instr covers 8 rows.
  const int rl  = lane >> 3;              // 0..7 row within 8-row group
  const int cb  = (lane & 7) ^ rl;        // swizzled global 16B-chunk for this lane
  const int srow = wave * 32 + rl;
  const ushort* gA0 = A  + (bm + srow) * (long)K + cb * 8;
  const ushort* gB0 = Bm + (bn + srow) * (long)K + cb * 8;
  ushort* lA[4]; ushort* lB[4];
#pragma unroll
  for (int i = 0; i < 4; ++i) {
    lA[i] = &As[(wave * 32 + 8 * i) * 64];
    lB[i] = &Bs[(wave * 32 + 8 * i) * 64];
  }

  // fragment-read swizzled slots (loop-invariant in rows): (kh*4+quad) ^ (l15&7)
  const int sq0 = ((0 * 4 + quad) ^ (l15 & 7)) * 8;
  const int sq1 = ((1 * 4 + quad) ^ (l15 & 7)) * 8;

  for (int k0 = 0; k0 < K; k0 += 64) {
#pragma unroll
    for (int i = 0; i < 4; ++i)
      __builtin_amdgcn_global_load_lds(
          (const __attribute__((address_space(1))) void*)(gA0 + 8L * i * K + k0),
          (__attribute__((address_space(3))) void*)lA[i], 16, 0, 0);
#pragma unroll
    for (int i = 0; i < 4; ++i)
      __builtin_amdgcn_global_load_lds(
          (const __attribute__((address_space(1))) void*)(gB0 + 8L * i * K + k0),
          (__attribute__((address_space(3))) void*)lB[i], 16, 0, 0);
    __syncthreads();   // drains vmcnt -> LDS tile ready

#pragma unroll
    for (int kh = 0; kh < 2; ++kh) {
      const int sq = kh ? sq1 : sq0;
      s16x8 af[4], bf[4];
#pragma unroll
      for (int mi = 0; mi < 4; ++mi)
        af[mi] = *reinterpret_cast<const s16x8*>(&As[(wm + mi * 16 + l15) * 64 + sq]);
#pragma unroll
      for (int ni = 0; ni < 4; ++ni)
        bf[ni] = *reinterpret_cast<const s16x8*>(&Bs[(wn + ni * 16 + l15) * 64 + sq]);
#pragma unroll
      for (int mi = 0; mi < 4; ++mi)
#pragma unroll
        for (int ni = 0; ni < 4; ++ni)
          acc[mi][ni] = mfma_bf16_16x16x32(af[mi], bf[ni], acc[mi][ni]);
    }
    __syncthreads();   // protect LDS before next stage
  }

  // epilogue: C/D layout col = lane&15, row = quad*4 + reg
#pragma unroll
  for (int mi = 0; mi < 4; ++mi) {
    const long mrow = bm + wm + mi * 16 + quad * 4;
#pragma unroll
    for (int ni = 0; ni < 4; ++ni) {
      const long ncol = bn + wn + ni * 16 + l15;
      const float bv = bias[ncol];
      if (OUT_BF16) {
        ushort* cp = (ushort*)Cv + mrow * (long)N + ncol;
#pragma unroll
        for (int r = 0; r < 4; ++r) cp[(long)r * N] = f2bf(acc[mi][ni][r] + bv);
      } else {
        float* cp = (float*)Cv + mrow * (long)N + ncol;
#pragma unroll
        for (int r = 0; r < 4; ++r) cp[(long)r * N] = acc[mi][ni][r] + bv;
      }
    }
  }
}

// ---- scan helpers ----
__device__ inline float softplus_f(float x) {
  return fmaxf(x, 0.f) + __logf(1.f + __expf(-fabsf(x)));
}
__device__ inline float logaddexp_f(float a, float b) {
  float m = fmaxf(a, b);
  return m + __logf(1.f + __expf(-fabsf(a - b)));
}
// from (hidden, gate): lc = -softplus(g); v = log_z + log_tilde_h
__device__ inline void transform_f(float hd, float g, float& lc, float& v) {
  float sp = softplus_f(g);
  lc = -sp;
  float lz = g - sp;                       // -softplus(-g)
  float lth = (hd >= 0.f) ? __logf(hd + 0.5f) : (hd - softplus_f(hd));
  v = lz + lth;
}

// phase 1: per (b, chunk, h-quad) compute chunk composition (Asum, Bv) for 4 channels
__global__ void scan_phase1(const ushort* __restrict__ hg,
                            float* __restrict__ Ac, float* __restrict__ Bc) {
  int gid = blockIdx.x * blockDim.x + threadIdx.x;  // B_*NC_*H_/4
  int hq = gid & (H_ / 4 - 1);       // h/4, 0..255
  int c  = (gid >> 8) & (NC_ - 1);
  int b  = gid >> 16;
  const ushort* p = hg + ((size_t)(b * L_ + c * LC_) * (2 * H_)) + hq * 4;
  float As[4] = {0.f, 0.f, 0.f, 0.f};
  float Bv[4] = {-INFINITY, -INFINITY, -INFINITY, -INFINITY};
#pragma unroll 4
  for (int l = 0; l < LC_; ++l) {
    ushort4 hd4 = *reinterpret_cast<const ushort4*>(p);
    ushort4 g4  = *reinterpret_cast<const ushort4*>(p + H_);
    float hdv[4] = {bf2f(hd4.x), bf2f(hd4.y), bf2f(hd4.z), bf2f(hd4.w)};
    float gv[4]  = {bf2f(g4.x),  bf2f(g4.y),  bf2f(g4.z),  bf2f(g4.w)};
#pragma unroll
    for (int j = 0; j < 4; ++j) {
      float lc, v; transform_f(hdv[j], gv[j], lc, v);
      As[j] += lc;
      Bv[j] = logaddexp_f(Bv[j] + lc, v);
    }
    p += 2 * H_;
  }
  size_t o = (size_t)(b * NC_ + c) * H_ + hq * 4;
  *reinterpret_cast<float4*>(&Ac[o]) = make_float4(As[0], As[1], As[2], As[3]);
  *reinterpret_cast<float4*>(&Bc[o]) = make_float4(Bv[0], Bv[1], Bv[2], Bv[3]);
}

// phase 2: per (b, h) exclusive scan over chunk summaries -> carry (incoming log_h per chunk)
__global__ void scan_phase2(const float* __restrict__ Ac, const float* __restrict__ Bc,
                            float* __restrict__ carry) {
  int gid = blockIdx.x * blockDim.x + threadIdx.x;  // B_*H_
  int h = gid & (H_ - 1);
  int b = gid >> 10;
  float P = -INFINITY;
  for (int c = 0; c < NC_; ++c) {
    size_t o = (size_t)(b * NC_ + c) * H_ + h;
    carry[o] = P;
    P = logaddexp_f(P + Ac[o], Bc[o]);
  }
}

// phase 3: re-scan chunk with carry, emit h = exp(log_h) as bf16 (4 channels/thread)
__global__ void scan_phase3(const ushort* __restrict__ hg, const float* __restrict__ carry,
                            ushort* __restrict__ hb) {
  int gid = blockIdx.x * blockDim.x + threadIdx.x;  // B_*NC_*H_/4
  int hq = gid & (H_ / 4 - 1);
  int c  = (gid >> 8) & (NC_ - 1);
  int b  = gid >> 16;
  float4 cr = *reinterpret_cast<const float4*>(&carry[(size_t)(b * NC_ + c) * H_ + hq * 4]);
  float lh[4] = {cr.x, cr.y, cr.z, cr.w};
  const ushort* p = hg + ((size_t)(b * L_ + c * LC_) * (2 * H_)) + hq * 4;
  ushort* q = hb + (size_t)(b * L_ + c * LC_) * H_ + hq * 4;
#pragma unroll 4
  for (int l = 0; l < LC_; ++l) {
    ushort4 hd4 = *reinterpret_cast<const ushort4*>(p);
    ushort4 g4  = *reinterpret_cast<const ushort4*>(p + H_);
    float hdv[4] = {bf2f(hd4.x), bf2f(hd4.y), bf2f(hd4.z), bf2f(hd4.w)};
    float gv[4]  = {bf2f(g4.x),  bf2f(g4.y),  bf2f(g4.z),  bf2f(g4.w)};
    ushort4 o;
    ushort* op = &o.x;
#pragma unroll
    for (int j = 0; j < 4; ++j) {
      float lc, v; transform_f(hdv[j], gv[j], lc, v);
      lh[j] = logaddexp_f(lh[j] + lc, v);
      op[j] = f2bf(__expf(lh[j]));
    }
    *reinterpret_cast<ushort4*>(q) = o;
    p += 2 * H_;
    q += H_;
  }
}

extern "C" void kernel_launch(void* const* d_in, const int* in_sizes, int n_in,
                              void* d_out, int out_size, void* d_ws, size_t ws_size,
                              hipStream_t stream) {
  const float* x     = (const float*)d_in[0];
  const float* W_in  = (const float*)d_in[1];
  const float* b_in  = (const float*)d_in[2];
  const float* W_out = (const float*)d_in[3];
  const float* b_out = (const float*)d_in[4];
  float* out = (float*)d_out;

  char* ws = (char*)d_ws;
  size_t off = 0;
  auto alloc = [&](size_t bytes) {
    void* p = ws + off;
    off = (off + bytes + 255) & ~(size_t)255;
    return p;
  };
  // region shared by xb (alive: cast -> GEMM1) and hb (alive: phase3 -> GEMM2)
  ushort* xb    = (ushort*)alloc((size_t)B_ * L_ * H_ * 2);       // 67 MB (union)
  ushort* hb    = xb;
  ushort* Wib   = (ushort*)alloc((size_t)2 * H_ * D_ * 2);        // 2 MB
  ushort* Wob   = (ushort*)alloc((size_t)D_ * H_ * 2);            // 1 MB
  ushort* hgb   = (ushort*)alloc((size_t)B_ * L_ * 2 * H_ * 2);   // 134 MB (bf16)
  float*  Ac    = (float*)alloc((size_t)B_ * NC_ * H_ * 4);       // 4 MB
  float*  Bc    = (float*)alloc((size_t)B_ * NC_ * H_ * 4);       // 4 MB
  float*  carry = (float*)alloc((size_t)B_ * NC_ * H_ * 4);       // 4 MB
  // total ~216 MB

  // casts to bf16
  cast_kernel<<<(B_ * L_ * D_ / 4 + 255) / 256, 256, 0, stream>>>(x, xb, B_ * L_ * D_ / 4);
  {
    int n0 = 2 * H_ * D_ / 4, n1 = D_ * H_ / 4;
    cast2_kernel<<<(n0 + n1 + 255) / 256, 256, 0, stream>>>(W_in, Wib, n0, W_out, Wob, n1);
  }

  // GEMM1: hg = x . W_in^T + b_in   (M=32768, N=2048, K=512), bf16 out
  gemm_bt<true><<<dim3((2 * H_) / 128, (B_ * L_) / 128), 256, 0, stream>>>(
      xb, Wib, b_in, hgb, B_ * L_, 2 * H_, D_);

  // chunked scan along L (4 channels per thread)
  scan_phase1<<<(B_ * NC_ * H_ / 4) / 256, 256, 0, stream>>>(hgb, Ac, Bc);
  scan_phase2<<<(B_ * H_) / 256, 256, 0, stream>>>(Ac, Bc, carry);
  scan_phase3<<<(B_ * NC_ * H_ / 4) / 256, 256, 0, stream>>>(hgb, carry, hb);

  // GEMM2: out = h . W_out^T + b_out   (M=32768, N=512, K=1024), fp32 out
  gemm_bt<false><<<dim3(D_ / 128, (B_ * L_) / 128), 256, 0, stream>>>(
      hb, Wob, b_out, out, B_ * L_, D_, H_);
}